// Round 1
// 321.634 us; speedup vs baseline: 1.2047x; 1.2047x over previous
//
#include <hip/hip_runtime.h>
#include <stdint.h>

#define TS 2048
#define CD 128
#define NB 8
#define NROWS (NB*TS)          // 16384
#define RPB 8                  // rows per block in projection kernels
#define SCALE 0.08838834764831845f  // 1/sqrt(128)
#define JSPLIT 4

// ---- scores kernel geometry (MFMA version) ----
#define QT 128                 // q-rows per block (4 waves x 32 rows)
#define KT 64                  // keys per staged tile
#define KRANGE (TS/JSPLIT)     // 512 keys per block
#define NKT (KRANGE/KT)        // 8 key-tiles
#define CSTR 97                // candidate merge row stride (floats), 97%32=1 -> conflict-free

typedef _Float16 f16x8 __attribute__((ext_vector_type(8)));
typedef float    f32x4 __attribute__((ext_vector_type(4)));

__device__ __forceinline__ void gload_lds16(const void* g, void* l) {
    __builtin_amdgcn_global_load_lds(
        (const __attribute__((address_space(1))) void*)g,
        (__attribute__((address_space(3))) void*)l, 16, 0, 0);
}

// ---- Kernel 1: Q = E@Wq^T, K = E@Wk^T, emitted as packed f16 hi/lo ----
// Layout: Qc[row][0..127]=hi, Qc[row][128..255]=lo  (row stride 256 halves = 512 B)
__global__ __launch_bounds__(128) void proj_qk(
    const float* __restrict__ E, const float* __restrict__ Wq,
    const float* __restrict__ Wk, _Float16* __restrict__ Qc, _Float16* __restrict__ Kc)
{
    const int r0 = blockIdx.x * RPB, t = threadIdx.x;
    __shared__ float e[RPB][CD];
    {
        const float4* src = (const float4*)(E + (size_t)r0*CD);
        float4* dst = (float4*)&e[0][0];
        dst[t] = src[t];
        dst[t + 128] = src[t + 128];
    }
    __syncthreads();
    const float* wq = Wq + (size_t)t*CD;
    const float* wk = Wk + (size_t)t*CD;
    float aq[RPB], ak[RPB];
    #pragma unroll
    for (int i = 0; i < RPB; i++) { aq[i] = 0.f; ak[i] = 0.f; }
    #pragma unroll
    for (int c = 0; c < CD; c += 4) {
        float4 a = *(const float4*)(wq + c);
        float4 b = *(const float4*)(wk + c);
        #pragma unroll
        for (int i = 0; i < RPB; i++) {
            float e0 = e[i][c+0], e1 = e[i][c+1], e2 = e[i][c+2], e3 = e[i][c+3];
            aq[i] += a.x*e0 + a.y*e1 + a.z*e2 + a.w*e3;
            ak[i] += b.x*e0 + b.y*e1 + b.z*e2 + b.w*e3;
        }
    }
    #pragma unroll
    for (int i = 0; i < RPB; i++) {
        float q = aq[i], k = ak[i];
        _Float16 qh = (_Float16)q, kh = (_Float16)k;
        _Float16 ql = (_Float16)(q - (float)qh);
        _Float16 kl = (_Float16)(k - (float)kh);
        const size_t rb = (size_t)(r0+i)*256;
        Qc[rb + t] = qh; Qc[rb + 128 + t] = ql;
        Kc[rb + t] = kh; Kc[rb + 128 + t] = kl;
    }
}

// top-3 insert, strict > keeps earliest (= smallest) index on ties
#define UPD(v, jg, s) do { \
    if ((v) > tv2[s]) { \
        if ((v) > tv0[s]) { tv2[s]=tv1[s]; ti2[s]=ti1[s]; tv1[s]=tv0[s]; ti1[s]=ti0[s]; tv0[s]=(v); ti0[s]=(jg); } \
        else if ((v) > tv1[s]) { tv2[s]=tv1[s]; ti2[s]=ti1[s]; tv1[s]=(v); ti1[s]=(jg); } \
        else { tv2[s]=(v); ti2[s]=(jg); } \
    } \
} while (0)

// ---- Kernel 2: MFMA f16 hi/lo 3-pass scores + per-(row,split) top-3 ----
// grid: 8n x 4sp x 16qt = 512 blocks; block: 256 threads (4 waves x 32 q-rows)
__global__ __launch_bounds__(256, 2) void scores_top3(
    const _Float16* __restrict__ Qc, const _Float16* __restrict__ Kc,
    float* __restrict__ SPL)
{
    const int b  = blockIdx.x;
    const int n  = b >> 6;
    const int sp = (b >> 4) & 3;
    const int qt = b & 15;
    const int q0 = qt * QT;
    const int j0 = sp * KRANGE;
    const int tid = threadIdx.x;
    const int w = tid >> 6, l = tid & 63;
    const int m = l & 15;

    __shared__ __align__(16) char lds[65536];   // 2 x 32KB K-tile dbuf; reused for merge

    // ---- A (Q) fragments: resident for the whole kernel ----
    // qa[rt][h][c4]: rt = 16-row tile, h = hi/lo, c4 = 32-wide k-chunk
    // lane layout: A[row = l&15][k = (l>>4)*8 + j]  (8 contiguous halves = 16 B)
    f16x8 qa[2][2][4];
    {
        const char* qb = (const char*)Qc + (size_t)(n*TS + q0 + w*32) * 512;
        #pragma unroll
        for (int rt = 0; rt < 2; rt++)
            #pragma unroll
            for (int h = 0; h < 2; h++)
                #pragma unroll
                for (int c4 = 0; c4 < 4; c4++)
                    qa[rt][h][c4] = *(const f16x8*)(qb + (size_t)(rt*16 + m)*512
                                                    + (h*256 + c4*64 + ((l>>4)<<4)));
    }

    // ---- staging source: pre-swizzled global addr so linear global_load_lds
    //      dest yields LDS[key*512 + (coff ^ ((key&7)<<4))] = K[key*512 + coff]
    const int keyb = w*2 + (l>>5);                       // key (mod 8) this lane stages
    const char* psrc = (const char*)Kc + (size_t)(n*TS + j0)*512
                       + keyb*512 + (((l&31)*16) ^ (keyb<<4));
    char* ldsw = lds + w*1024;

    float tv0[8], tv1[8], tv2[8];
    int   ti0[8], ti1[8], ti2[8];
    #pragma unroll
    for (int s = 0; s < 8; s++) {
        tv0[s]=tv1[s]=tv2[s] = -3e38f;
        ti0[s]=ti1[s]=ti2[s] = 0x7fffffff;
    }

    // prologue: stage tile 0 into buf 0
    #pragma unroll
    for (int i = 0; i < 8; i++) gload_lds16(psrc + i*4096, ldsw + i*4096);

    int cur = 0;
    #pragma unroll 1
    for (int kt = 0; kt < NKT; kt++) {
        __syncthreads();                       // drains staging of buf[cur]
        if (kt + 1 < NKT) {                    // async-stage next tile into other buffer
            const char* s_ = psrc + (size_t)(kt+1)*32768;
            char* d_ = ldsw + ((cur^1) << 15);
            #pragma unroll
            for (int i = 0; i < 8; i++) gload_lds16(s_ + i*4096, d_ + i*4096);
        }
        const char* kb = lds + (cur << 15);

        f32x4 acc[2][4];
        #pragma unroll
        for (int rt = 0; rt < 2; rt++)
            #pragma unroll
            for (int ct = 0; ct < 4; ct++) acc[rt][ct] = (f32x4){0.f,0.f,0.f,0.f};

        const int swzl = (l & 7) << 4;
        const int lo16 = (l >> 4) << 4;
        #pragma unroll
        for (int ct = 0; ct < 4; ct++) {
            const char* bb = kb + (size_t)(ct*16 + m)*512;   // key row = ct*16 + (l&15)
            f16x8 kh[4];
            #pragma unroll
            for (int c4 = 0; c4 < 4; c4++)
                kh[c4] = *(const f16x8*)(bb + ((c4*64 + lo16) ^ swzl));
            // pass 1: hi_q * hi_k
            #pragma unroll
            for (int c4 = 0; c4 < 4; c4++) {
                acc[0][ct] = __builtin_amdgcn_mfma_f32_16x16x32_f16(qa[0][0][c4], kh[c4], acc[0][ct], 0,0,0);
                acc[1][ct] = __builtin_amdgcn_mfma_f32_16x16x32_f16(qa[1][0][c4], kh[c4], acc[1][ct], 0,0,0);
            }
            // pass 2: lo_q * hi_k
            #pragma unroll
            for (int c4 = 0; c4 < 4; c4++) {
                acc[0][ct] = __builtin_amdgcn_mfma_f32_16x16x32_f16(qa[0][1][c4], kh[c4], acc[0][ct], 0,0,0);
                acc[1][ct] = __builtin_amdgcn_mfma_f32_16x16x32_f16(qa[1][1][c4], kh[c4], acc[1][ct], 0,0,0);
            }
            // pass 3: hi_q * lo_k
            f16x8 kl[4];
            #pragma unroll
            for (int c4 = 0; c4 < 4; c4++)
                kl[c4] = *(const f16x8*)(bb + ((256 + c4*64 + lo16) ^ swzl));
            #pragma unroll
            for (int c4 = 0; c4 < 4; c4++) {
                acc[0][ct] = __builtin_amdgcn_mfma_f32_16x16x32_f16(qa[0][0][c4], kl[c4], acc[0][ct], 0,0,0);
                acc[1][ct] = __builtin_amdgcn_mfma_f32_16x16x32_f16(qa[1][0][c4], kl[c4], acc[1][ct], 0,0,0);
            }
        }

        // ---- top-3 update: C/D layout col = l&15 (key), row = (l>>4)*4 + reg ----
        const int jb = j0 + kt*KT;
        #pragma unroll
        for (int rt = 0; rt < 2; rt++)
            #pragma unroll
            for (int rg = 0; rg < 4; rg++) {
                const int s = rt*4 + rg;
                float a0 = acc[rt][0][rg], a1 = acc[rt][1][rg];
                float a2 = acc[rt][2][rg], a3 = acc[rt][3][rg];
                float mx = fmaxf(fmaxf(a0,a1), fmaxf(a2,a3));
                if (mx > tv2[s]) {             // rare after warmup; asc order keeps tie semantics
                    UPD(a0, jb +      m, s);
                    UPD(a1, jb + 16 + m, s);
                    UPD(a2, jb + 32 + m, s);
                    UPD(a3, jb + 48 + m, s);
                }
            }
        cur ^= 1;
    }

    // ---- block merge: 16 lanes x 3 candidates per row -> per-(row,split) top-3 ----
    __syncthreads();                           // all LDS tile reads done; overlay buffer
    float* cand = (float*)lds;                 // [128 rows][CSTR]
    #pragma unroll
    for (int rt = 0; rt < 2; rt++)
        #pragma unroll
        for (int rg = 0; rg < 4; rg++) {
            const int s = rt*4 + rg;
            const int row = w*32 + rt*16 + ((l>>4)<<2) + rg;
            float* c = cand + (size_t)row*CSTR + m*6;
            c[0] = tv0[s]; c[1] = __int_as_float(ti0[s]);
            c[2] = tv1[s]; c[3] = __int_as_float(ti1[s]);
            c[4] = tv2[s]; c[5] = __int_as_float(ti2[s]);
        }
    __syncthreads();
    if (tid < QT) {
        float b0v = -3e38f, b1v = -3e38f, b2v = -3e38f;
        int   b0i = 0x7fffffff, b1i = 0x7fffffff, b2i = 0x7fffffff;
        const float* mm = cand + (size_t)tid*CSTR;
        for (int t2 = 0; t2 < 16; t2++) {
            #pragma unroll
            for (int k = 0; k < 3; k++) {
                float v = mm[t2*6 + 2*k];
                int  id = __float_as_int(mm[t2*6 + 2*k + 1]);
                bool g2 = (v > b2v) || (v == b2v && id < b2i);
                if (g2) {
                    bool g0 = (v > b0v) || (v == b0v && id < b0i);
                    bool g1 = (v > b1v) || (v == b1v && id < b1i);
                    if (g0)      { b2v=b1v;b2i=b1i; b1v=b0v;b1i=b0i; b0v=v;b0i=id; }
                    else if (g1) { b2v=b1v;b2i=b1i; b1v=v;  b1i=id; }
                    else         { b2v=v;  b2i=id; }
                }
            }
        }
        const int row = n*TS + q0 + tid;
        float* dst = SPL + ((size_t)row*JSPLIT + sp)*8;
        dst[0] = b0v; dst[1] = __int_as_float(b0i);
        dst[2] = b1v; dst[3] = __int_as_float(b1i);
        dst[4] = b2v; dst[5] = __int_as_float(b2i);
    }
}

// ---- Kernel 3: merge 4 splits per row -> global top-3 + 3-term softmax ----
__global__ __launch_bounds__(256) void merge_splits(
    const float* __restrict__ SPL, float* __restrict__ TOP)
{
    const int row = blockIdx.x*256 + threadIdx.x;   // 64 blocks -> 16384 rows
    const float* s = SPL + (size_t)row*JSPLIT*8;
    float b0v = -3e38f, b1v = -3e38f, b2v = -3e38f;
    int   b0i = 0x7fffffff, b1i = 0x7fffffff, b2i = 0x7fffffff;
    #pragma unroll
    for (int sp = 0; sp < JSPLIT; sp++) {
        #pragma unroll
        for (int k = 0; k < 3; k++) {
            float v = s[sp*8 + 2*k];
            int  id = __float_as_int(s[sp*8 + 2*k + 1]);
            bool g2 = (v > b2v) || (v == b2v && id < b2i);
            if (g2) {
                bool g0 = (v > b0v) || (v == b0v && id < b0i);
                bool g1 = (v > b1v) || (v == b1v && id < b1i);
                if (g0)      { b2v=b1v;b2i=b1i; b1v=b0v;b1i=b0i; b0v=v;b0i=id; }
                else if (g1) { b2v=b1v;b2i=b1i; b1v=v;  b1i=id; }
                else         { b2v=v;  b2i=id; }
            }
        }
    }
    float e1 = __expf((b1v - b0v)*SCALE);
    float e2 = __expf((b2v - b0v)*SCALE);
    float rz = 1.0f / (1.0f + e1 + e2);
    float* dst = TOP + (size_t)row*8;
    dst[0] = rz; dst[1] = e1*rz; dst[2] = e2*rz;
    int* di = (int*)dst;
    di[4] = b0i; di[5] = b1i; di[6] = b2i;
}

// ---- Kernel 4: materialize dense fp32 attention (zeros + 3 probs per row) ----
__global__ __launch_bounds__(256) void attn_write(
    const float* __restrict__ TOP, float* __restrict__ A)
{
    const int r = blockIdx.x, t = threadIdx.x;
    const float* s = TOP + (size_t)r*8;
    const int* si = (const int*)s;
    float p0 = s[0], p1 = s[1], p2 = s[2];
    int i0 = si[4], i1 = si[5], i2 = si[6];
    const int col0 = t*8;
    float vals[8];
    #pragma unroll
    for (int u = 0; u < 8; u++) {
        int col = col0 + u;
        float v = 0.f;
        if (col == i0) v = p0;
        if (col == i1) v = p1;
        if (col == i2) v = p2;
        vals[u] = v;
    }
    float4* dst = (float4*)(A + (size_t)r*TS + col0);
    dst[0] = make_float4(vals[0], vals[1], vals[2], vals[3]);
    dst[1] = make_float4(vals[4], vals[5], vals[6], vals[7]);
}

// ---- Kernel 5: out = (sum_k p_k * E[i_k]) @ Wo^T + bo, 8 rows per block ----
__global__ __launch_bounds__(128) void out_proj(
    const float* __restrict__ E, const float* __restrict__ Wo,
    const float* __restrict__ bo, const float* __restrict__ TOP,
    float* __restrict__ OUT)
{
    const int r0 = blockIdx.x * RPB, t = threadIdx.x;
    const int n = r0 >> 11;
    __shared__ float o[RPB][CD];
    #pragma unroll
    for (int i = 0; i < RPB; i++) {
        const float* s = TOP + (size_t)(r0+i)*8;
        const int* si = (const int*)s;
        const float* e0 = E + ((size_t)n*TS + si[4])*CD;
        const float* e1 = E + ((size_t)n*TS + si[5])*CD;
        const float* e2 = E + ((size_t)n*TS + si[6])*CD;
        o[i][t] = s[0]*e0[t] + s[1]*e1[t] + s[2]*e2[t];
    }
    __syncthreads();
    const float* wr = Wo + (size_t)t*CD;
    float acc[RPB];
    float bias = bo[t];
    #pragma unroll
    for (int i = 0; i < RPB; i++) acc[i] = bias;
    #pragma unroll
    for (int c = 0; c < CD; c += 4) {
        float4 a = *(const float4*)(wr + c);
        #pragma unroll
        for (int i = 0; i < RPB; i++)
            acc[i] += a.x*o[i][c+0] + a.y*o[i][c+1] + a.z*o[i][c+2] + a.w*o[i][c+3];
    }
    #pragma unroll
    for (int i = 0; i < RPB; i++)
        OUT[(size_t)(r0+i)*CD + t] = acc[i];
}

extern "C" void kernel_launch(void* const* d_in, const int* in_sizes, int n_in,
                              void* d_out, int out_size, void* d_ws, size_t ws_size,
                              hipStream_t stream)
{
    const float* E  = (const float*)d_in[0];
    // d_in[1] = ac, unused by the forward pass
    const float* Wq = (const float*)d_in[2];
    const float* Wk = (const float*)d_in[3];
    const float* Wo = (const float*)d_in[4];
    const float* bo = (const float*)d_in[5];

    _Float16* Qc = (_Float16*)d_ws;                  // 16384 x 256 halves (8 MB)
    _Float16* Kc = Qc + (size_t)NROWS*256;           // 8 MB
    float* TOP   = (float*)(Kc + (size_t)NROWS*256); // 16384 x 8 fp32 (512 KB)

    float* OUT = (float*)d_out;                      // [N,T,C] fp32
    float* A   = OUT + (size_t)NROWS*CD;             // [N,1,T,T] fp32
    float* SPL = A;   // scratch: 16384x4x8 fp32 = 2 MB, parked in A,
                      // fully overwritten by attn_write afterwards

    proj_qk     <<<NROWS/RPB, 128, 0, stream>>>(E, Wq, Wk, Qc, Kc);
    scores_top3 <<<NB*(TS/QT)*JSPLIT, 256, 0, stream>>>(Qc, Kc, SPL);
    merge_splits<<<NROWS/256, 256, 0, stream>>>(SPL, TOP);
    attn_write  <<<NROWS,     256, 0, stream>>>(TOP, A);
    out_proj    <<<NROWS/RPB, 128, 0, stream>>>(E, Wo, bo, TOP, OUT);
}

// Round 3
// 284.497 us; speedup vs baseline: 1.3620x; 1.1305x over previous
//
#include <hip/hip_runtime.h>
#include <stdint.h>

#define TS 2048
#define CD 128
#define NB 8
#define NROWS (NB*TS)          // 16384
#define RPB 8                  // rows per block in projection kernels
#define SCALE 0.08838834764831845f  // 1/sqrt(128)

// ---- scores kernel geometry ----
#define JSPLIT 8
#define QT 64                  // q-rows per block (4 waves x 16 rows)
#define KT 32                  // keys per staged tile (16 KB)
#define KRANGE (TS/JSPLIT)     // 256 keys per block
#define NKT (KRANGE/KT)        // 8 tiles
#define CSTR 97                // merge row stride: 16 lanes x 6 + 1

typedef _Float16 f16x8 __attribute__((ext_vector_type(8)));
typedef float    f32x4 __attribute__((ext_vector_type(4)));

__device__ __forceinline__ void gload_lds16(const void* g, void* l) {
    __builtin_amdgcn_global_load_lds(
        (const __attribute__((address_space(1))) void*)g,
        (__attribute__((address_space(3))) void*)l, 16, 0, 0);
}

// ---- Kernel 1: Q = E@Wq^T, K = E@Wk^T, emitted as packed f16 hi/lo ----
// Layout: Qc[row][0..127]=hi, Qc[row][128..255]=lo  (row stride 256 halves = 512 B)
__global__ __launch_bounds__(128) void proj_qk(
    const float* __restrict__ E, const float* __restrict__ Wq,
    const float* __restrict__ Wk, _Float16* __restrict__ Qc, _Float16* __restrict__ Kc)
{
    const int r0 = blockIdx.x * RPB, t = threadIdx.x;
    __shared__ float e[RPB][CD];
    {
        const float4* src = (const float4*)(E + (size_t)r0*CD);
        float4* dst = (float4*)&e[0][0];
        dst[t] = src[t];
        dst[t + 128] = src[t + 128];
    }
    __syncthreads();
    const float* wq = Wq + (size_t)t*CD;
    const float* wk = Wk + (size_t)t*CD;
    float aq[RPB], ak[RPB];
    #pragma unroll
    for (int i = 0; i < RPB; i++) { aq[i] = 0.f; ak[i] = 0.f; }
    #pragma unroll
    for (int c = 0; c < CD; c += 4) {
        float4 a = *(const float4*)(wq + c);
        float4 b = *(const float4*)(wk + c);
        #pragma unroll
        for (int i = 0; i < RPB; i++) {
            float e0 = e[i][c+0], e1 = e[i][c+1], e2 = e[i][c+2], e3 = e[i][c+3];
            aq[i] += a.x*e0 + a.y*e1 + a.z*e2 + a.w*e3;
            ak[i] += b.x*e0 + b.y*e1 + b.z*e2 + b.w*e3;
        }
    }
    #pragma unroll
    for (int i = 0; i < RPB; i++) {
        float q = aq[i], k = ak[i];
        _Float16 qh = (_Float16)q, kh = (_Float16)k;
        _Float16 ql = (_Float16)(q - (float)qh);
        _Float16 kl = (_Float16)(k - (float)kh);
        const size_t rb = (size_t)(r0+i)*256;
        Qc[rb + t] = qh; Qc[rb + 128 + t] = ql;
        Kc[rb + t] = kh; Kc[rb + 128 + t] = kl;
    }
}

// gated top-3 insert (round-1 verified; strict > keeps earliest index on ties)
#define UPD(v, jg, s) do { \
    if ((v) > tv2[s]) { \
        if ((v) > tv0[s]) { tv2[s]=tv1[s]; ti2[s]=ti1[s]; tv1[s]=tv0[s]; ti1[s]=ti0[s]; tv0[s]=(v); ti0[s]=(jg); } \
        else if ((v) > tv1[s]) { tv2[s]=tv1[s]; ti2[s]=ti1[s]; tv1[s]=(v); ti1[s]=(jg); } \
        else { tv2[s]=(v); ti2[s]=(jg); } \
    } \
} while (0)

// ---- Kernel 2: MFMA f16 hi/lo scores + per-(row,split) top-3 ----
// grid: 2048 blocks (8n x 8sp x 32qt, XCD-swizzled); 256 thr = 4 waves x 16 q-rows.
// LDS tile (16KB): [key][512B] rows, byte c holds K[key][c ^ ((key&7)<<4)]
// (round-1 verified swizzle scheme, scaled KT 64->32).
__global__ __launch_bounds__(256, 4) void scores_top3(
    const _Float16* __restrict__ Qc, const _Float16* __restrict__ Kc,
    float* __restrict__ SPL)
{
    const int bid = blockIdx.x;
    const int swz = (bid & 7) * 256 + (bid >> 3);    // bijective: 2048 % 8 == 0
    const int n  = swz >> 8;
    const int sp = (swz >> 5) & 7;
    const int qt = swz & 31;
    const int q0 = qt * QT;
    const int j0 = sp * KRANGE;
    const int tid = threadIdx.x;
    const int w = tid >> 6, l = tid & 63;
    const int m = l & 15, hi = l >> 4;

    __shared__ __align__(16) char lds[32768];        // 2 x 16KB dbuf; merge overlay 24832B

    // ---- Q (A-operand) fragments, resident: qa[plane][c4]
    // lane layout: A[row = l&15][k = (l>>4)*8 + j] of q rows w*16..w*16+15
    f16x8 qa[2][4];
    {
        const char* qb = (const char*)Qc + (size_t)(n*TS + q0 + w*16)*512;
        #pragma unroll
        for (int h = 0; h < 2; h++)
            #pragma unroll
            for (int c4 = 0; c4 < 4; c4++)
                qa[h][c4] = *(const f16x8*)(qb + m*512 + h*256 + c4*64 + hi*16);
    }

    // ---- staging: wave w stages 4KB/tile via 4 instrs.
    // dest byte = w*4096 + i*1024 + l*16  ->  key = w*8 + i*2 + (l>>5), coff = (l&31)*16
    // source = Kc[n*TS + j0 + key][coff ^ ((key&7)<<4)]   (key&7 = i*2 + (l>>5))
    const char* kcb = (const char*)Kc + (size_t)(n*TS + j0)*512;
    const char* ps[4];
    {
        const int ksub = l >> 5, coff = (l & 31) * 16;
        #pragma unroll
        for (int i = 0; i < 4; i++) {
            const int key = w*8 + i*2 + ksub;
            ps[i] = kcb + key*512 + (coff ^ ((i*2 + ksub) << 4));
        }
    }
    char* ldsw = lds + w*4096;

    float tv0[4], tv1[4], tv2[4];
    int   ti0[4], ti1[4], ti2[4];
    #pragma unroll
    for (int s = 0; s < 4; s++) {
        tv0[s]=tv1[s]=tv2[s] = -3e38f;
        ti0[s]=ti1[s]=ti2[s] = 0x7fffffff;
    }

    #pragma unroll
    for (int i = 0; i < 4; i++)                      // prologue: tile 0 -> buf 0
        gload_lds16(ps[i], ldsw + i*1024);

    const int swzl = (l & 7) << 4;
    const int lo16 = hi << 4;

    int cur = 0;
    #pragma unroll 1
    for (int kt = 0; kt < NKT; kt++) {
        __syncthreads();                             // buf[cur] staged & visible
        if (kt + 1 < NKT) {                          // async-stage next tile
            char* d_ = ldsw + ((cur^1) << 14);
            #pragma unroll
            for (int i = 0; i < 4; i++)
                gload_lds16(ps[i] + (size_t)(kt+1)*16384, d_ + i*1024);
        }
        const char* kb = lds + (cur << 14);

        f32x4 acc[2];
        acc[0] = (f32x4){0.f,0.f,0.f,0.f};
        acc[1] = (f32x4){0.f,0.f,0.f,0.f};

        __builtin_amdgcn_s_setprio(1);
        #pragma unroll
        for (int ct = 0; ct < 2; ct++) {
            const char* bb = kb + (size_t)(ct*16 + m)*512;   // key row = ct*16 + (l&15)
            f16x8 kh[4];
            #pragma unroll
            for (int c4 = 0; c4 < 4; c4++)
                kh[c4] = *(const f16x8*)(bb + ((c4*64 + lo16) ^ swzl));
            #pragma unroll
            for (int c4 = 0; c4 < 4; c4++)           // pass 1: qh * kh
                acc[ct] = __builtin_amdgcn_mfma_f32_16x16x32_f16(qa[0][c4], kh[c4], acc[ct], 0,0,0);
            #pragma unroll
            for (int c4 = 0; c4 < 4; c4++)           // pass 2: ql * kh
                acc[ct] = __builtin_amdgcn_mfma_f32_16x16x32_f16(qa[1][c4], kh[c4], acc[ct], 0,0,0);
            #pragma unroll
            for (int c4 = 0; c4 < 4; c4++) {         // pass 3: qh * kl
                f16x8 kl = *(const f16x8*)(bb + ((256 + c4*64 + lo16) ^ swzl));
                acc[ct] = __builtin_amdgcn_mfma_f32_16x16x32_f16(qa[0][c4], kl, acc[ct], 0,0,0);
            }
        }
        __builtin_amdgcn_s_setprio(0);

        // ---- top-3: C/D row = hi*4+rg = q-within-16 (slot rg), col = m = key-within-16
        const int jb = j0 + kt*KT;
        #pragma unroll
        for (int rg = 0; rg < 4; rg++) {
            float a0 = acc[0][rg], a1 = acc[1][rg];
            float mx = fmaxf(a0, a1);
            if (mx > tv2[rg]) {                      // ascending ct keeps tie semantics
                UPD(a0, jb + m, rg);
                UPD(a1, jb + 16 + m, rg);
            }
        }
        cur ^= 1;
    }

    // ---- block merge: 16 m-lanes x 3 cands per row -> per-(row,split) top-3 ----
    __syncthreads();                                 // all tile reads done; overlay
    float* cand = (float*)lds;                       // [64 rows][CSTR]
    #pragma unroll
    for (int rg = 0; rg < 4; rg++) {
        const int row = w*16 + hi*4 + rg;
        float* cc = cand + row*CSTR + m*6;
        cc[0] = tv0[rg]; cc[1] = __int_as_float(ti0[rg]);
        cc[2] = tv1[rg]; cc[3] = __int_as_float(ti1[rg]);
        cc[4] = tv2[rg]; cc[5] = __int_as_float(ti2[rg]);
    }
    __syncthreads();
    if (tid < QT) {
        float b0v = -3e38f, b1v = -3e38f, b2v = -3e38f;
        int   b0i = 0x7fffffff, b1i = 0x7fffffff, b2i = 0x7fffffff;
        const float* mm = cand + (size_t)tid*CSTR;
        for (int t2 = 0; t2 < 16; t2++) {
            #pragma unroll
            for (int k = 0; k < 3; k++) {
                float v = mm[t2*6 + 2*k];
                int  id = __float_as_int(mm[t2*6 + 2*k + 1]);
                bool g2 = (v > b2v) || (v == b2v && id < b2i);
                if (g2) {
                    bool g0 = (v > b0v) || (v == b0v && id < b0i);
                    bool g1 = (v > b1v) || (v == b1v && id < b1i);
                    if (g0)      { b2v=b1v;b2i=b1i; b1v=b0v;b1i=b0i; b0v=v;b0i=id; }
                    else if (g1) { b2v=b1v;b2i=b1i; b1v=v;  b1i=id; }
                    else         { b2v=v;  b2i=id; }
                }
            }
        }
        const int row = n*TS + q0 + tid;
        float* dst = SPL + ((size_t)row*JSPLIT + sp)*8;
        dst[0] = b0v; dst[1] = __int_as_float(b0i);
        dst[2] = b1v; dst[3] = __int_as_float(b1i);
        dst[4] = b2v; dst[5] = __int_as_float(b2i);
    }
}

// ---- Kernel 3: merge splits per row -> global top-3 + 3-term softmax ----
__global__ __launch_bounds__(256) void merge_splits(
    const float* __restrict__ SPL, float* __restrict__ TOP)
{
    const int row = blockIdx.x*256 + threadIdx.x;   // 64 blocks -> 16384 rows
    const float* s = SPL + (size_t)row*JSPLIT*8;
    float b0v = -3e38f, b1v = -3e38f, b2v = -3e38f;
    int   b0i = 0x7fffffff, b1i = 0x7fffffff, b2i = 0x7fffffff;
    #pragma unroll
    for (int sp = 0; sp < JSPLIT; sp++) {
        #pragma unroll
        for (int k = 0; k < 3; k++) {
            float v = s[sp*8 + 2*k];
            int  id = __float_as_int(s[sp*8 + 2*k + 1]);
            bool g2 = (v > b2v) || (v == b2v && id < b2i);
            if (g2) {
                bool g0 = (v > b0v) || (v == b0v && id < b0i);
                bool g1 = (v > b1v) || (v == b1v && id < b1i);
                if (g0)      { b2v=b1v;b2i=b1i; b1v=b0v;b1i=b0i; b0v=v;b0i=id; }
                else if (g1) { b2v=b1v;b2i=b1i; b1v=v;  b1i=id; }
                else         { b2v=v;  b2i=id; }
            }
        }
    }
    float e1 = __expf((b1v - b0v)*SCALE);
    float e2 = __expf((b2v - b0v)*SCALE);
    float rz = 1.0f / (1.0f + e1 + e2);
    float* dst = TOP + (size_t)row*8;
    dst[0] = rz; dst[1] = e1*rz; dst[2] = e2*rz;
    int* di = (int*)dst;
    di[4] = b0i; di[5] = b1i; di[6] = b2i;
}

// ---- Kernel 4: materialize dense fp32 attention (zeros + 3 probs per row) ----
__global__ __launch_bounds__(256) void attn_write(
    const float* __restrict__ TOP, float* __restrict__ A)
{
    const int r = blockIdx.x, t = threadIdx.x;
    const float* s = TOP + (size_t)r*8;
    const int* si = (const int*)s;
    float p0 = s[0], p1 = s[1], p2 = s[2];
    int i0 = si[4], i1 = si[5], i2 = si[6];
    const int col0 = t*8;
    float vals[8];
    #pragma unroll
    for (int u = 0; u < 8; u++) {
        int col = col0 + u;
        float v = 0.f;
        if (col == i0) v = p0;
        if (col == i1) v = p1;
        if (col == i2) v = p2;
        vals[u] = v;
    }
    float4* dst = (float4*)(A + (size_t)r*TS + col0);
    dst[0] = make_float4(vals[0], vals[1], vals[2], vals[3]);
    dst[1] = make_float4(vals[4], vals[5], vals[6], vals[7]);
}

// ---- Kernel 5: out = (sum_k p_k * E[i_k]) @ Wo^T + bo, 8 rows per block ----
__global__ __launch_bounds__(128) void out_proj(
    const float* __restrict__ E, const float* __restrict__ Wo,
    const float* __restrict__ bo, const float* __restrict__ TOP,
    float* __restrict__ OUT)
{
    const int r0 = blockIdx.x * RPB, t = threadIdx.x;
    const int n = r0 >> 11;
    __shared__ float o[RPB][CD];
    #pragma unroll
    for (int i = 0; i < RPB; i++) {
        const float* s = TOP + (size_t)(r0+i)*8;
        const int* si = (const int*)s;
        const float* e0 = E + ((size_t)n*TS + si[4])*CD;
        const float* e1 = E + ((size_t)n*TS + si[5])*CD;
        const float* e2 = E + ((size_t)n*TS + si[6])*CD;
        o[i][t] = s[0]*e0[t] + s[1]*e1[t] + s[2]*e2[t];
    }
    __syncthreads();
    const float* wr = Wo + (size_t)t*CD;
    float acc[RPB];
    float bias = bo[t];
    #pragma unroll
    for (int i = 0; i < RPB; i++) acc[i] = bias;
    #pragma unroll
    for (int c = 0; c < CD; c += 4) {
        float4 a = *(const float4*)(wr + c);
        #pragma unroll
        for (int i = 0; i < RPB; i++)
            acc[i] += a.x*o[i][c+0] + a.y*o[i][c+1] + a.z*o[i][c+2] + a.w*o[i][c+3];
    }
    #pragma unroll
    for (int i = 0; i < RPB; i++)
        OUT[(size_t)(r0+i)*CD + t] = acc[i];
}

extern "C" void kernel_launch(void* const* d_in, const int* in_sizes, int n_in,
                              void* d_out, int out_size, void* d_ws, size_t ws_size,
                              hipStream_t stream)
{
    const float* E  = (const float*)d_in[0];
    // d_in[1] = ac, unused by the forward pass
    const float* Wq = (const float*)d_in[2];
    const float* Wk = (const float*)d_in[3];
    const float* Wo = (const float*)d_in[4];
    const float* bo = (const float*)d_in[5];

    _Float16* Qc = (_Float16*)d_ws;                  // 16384 x 256 halves (8 MB)
    _Float16* Kc = Qc + (size_t)NROWS*256;           // 8 MB
    float* TOP   = (float*)(Kc + (size_t)NROWS*256); // 16384 x 8 fp32 (512 KB)

    float* OUT = (float*)d_out;                      // [N,T,C] fp32
    float* A   = OUT + (size_t)NROWS*CD;             // [N,1,T,T] fp32
    float* SPL = A;   // scratch: 16384x8x8 fp32 = 4 MB, parked in A,
                      // consumed by merge_splits then overwritten by attn_write

    proj_qk     <<<NROWS/RPB, 128, 0, stream>>>(E, Wq, Wk, Qc, Kc);
    scores_top3 <<<NB*(TS/QT)*JSPLIT, 256, 0, stream>>>(Qc, Kc, SPL);
    merge_splits<<<NROWS/256, 256, 0, stream>>>(SPL, TOP);
    attn_write  <<<NROWS,     256, 0, stream>>>(TOP, A);
    out_proj    <<<NROWS/RPB, 128, 0, stream>>>(E, Wo, bo, TOP, OUT);
}